// Round 1
// 2550.950 us; speedup vs baseline: 1.2557x; 1.2557x over previous
//
#include <hip/hip_runtime.h>
#include <hip/hip_bf16.h>
#include <math.h>

#define BB 2
#define SS 4096
#define DDIM 2560
#define MMEM 128
#define NH 8
#define HDIM 320
#define SEG 1024
#define NSEG 4

typedef unsigned short u16;
typedef __attribute__((ext_vector_type(8))) short short8;
typedef __attribute__((ext_vector_type(4))) float f32x4;

__device__ __forceinline__ u16 f2b(float x) {
  __hip_bfloat16 h = __float2bfloat16(x);
  return *reinterpret_cast<u16*>(&h);
}

__device__ __forceinline__ void gll16(const u16* g, u16* l) {
  __builtin_amdgcn_global_load_lds(
      (__attribute__((address_space(1))) void*)g,
      (__attribute__((address_space(3))) void*)l, 16, 0, 0);
}

// Per-region output descriptor. Any non-null pointer gets written.
// f/b share geometry (ld, s1, s2); bt is bf16 transposed (ldt, s1, s2).
struct OutDesc {
  float* f; u16* b; u16* bt; const float* bias;
  long ld; long ldt; long s1; long s2;
};

// C = alpha * A @ Bt^T. A: (Mr x K) bf16 (Mr multiple of 128). Bt: (N x K) bf16.
// Region 0 covers cols [0,Nsplit), region 1 covers [Nsplit,N).
__global__ __launch_bounds__(256) void gemm_bt(
    const u16* __restrict__ A, const u16* __restrict__ Bt,
    OutDesc o0, OutDesc o1, int Nsplit,
    int N, int K, long lda, long ldb,
    long sA1, long sA2, long sB1, long sB2,
    int Z1, float alpha)
{
  __shared__ __align__(16) u16 sm[8192];   // As[128][32] + Bs[128][32], unpadded
  u16* As = sm;
  u16* Bs = sm + 4096;

  int z = blockIdx.z;
  int z1 = z % Z1, z2 = z / Z1;
  const u16* Az = A + (long)z1 * sA1 + (long)z2 * sA2 + (long)blockIdx.x * 128 * lda;
  const u16* Bz = Bt + (long)z1 * sB1 + (long)z2 * sB2;

  int tN = blockIdx.y * 128;
  int t = threadIdx.x;
  int lane = t & 63, w = t >> 6;
  int wm = w & 1, wn = w >> 1;

  // ---- staging addresses (global_load_lds, 16B per lane) ----
  int rr = t >> 2;               // 0..63
  int c8 = (t & 3) << 3;         // 0,8,16,24
  int n0 = tN + rr;      if (n0 > N - 1) n0 = N - 1;   // clamp edge N tiles
  int n1 = tN + 64 + rr; if (n1 > N - 1) n1 = N - 1;
  const u16* ga0 = Az + (long)rr * lda + c8;
  const u16* ga1 = Az + (long)(rr + 64) * lda + c8;
  const u16* gb0 = Bz + (long)n0 * ldb + c8;
  const u16* gb1 = Bz + (long)n1 * ldb + c8;
  u16* lA0 = As + t * 8;         // lds dest = wave base + lane*16B (contiguous)
  u16* lA1 = As + 2048 + t * 8;
  u16* lB0 = Bs + t * 8;
  u16* lB1 = Bs + 2048 + t * 8;

  f32x4 acc[4][4];
#pragma unroll
  for (int i = 0; i < 4; i++)
#pragma unroll
    for (int j = 0; j < 4; j++) acc[i][j] = (f32x4){0.f, 0.f, 0.f, 0.f};

  int arow = lane & 15;
  int kq = (lane >> 4) << 3;

  for (int k0 = 0; k0 < K; k0 += 32) {
    gll16(ga0, lA0); gll16(ga1, lA1);
    gll16(gb0, lB0); gll16(gb1, lB1);
    ga0 += 32; ga1 += 32; gb0 += 32; gb1 += 32;
    __syncthreads();   // drains vmcnt, publishes LDS

    short8 af[4], bfr[4];
#pragma unroll
    for (int i = 0; i < 4; i++)
      af[i] = *(const short8*)(As + (wm * 64 + i * 16 + arow) * 32 + kq);
#pragma unroll
    for (int j = 0; j < 4; j++)
      bfr[j] = *(const short8*)(Bs + (wn * 64 + j * 16 + arow) * 32 + kq);
#pragma unroll
    for (int i = 0; i < 4; i++)
#pragma unroll
      for (int j = 0; j < 4; j++)
        acc[i][j] = __builtin_amdgcn_mfma_f32_16x16x32_bf16(af[i], bfr[j], acc[i][j], 0, 0, 0);
    __syncthreads();   // all waves done reading before next overwrite
  }

  // ---- epilogue ----
  int rowb = blockIdx.x * 128 + wm * 64 + ((lane >> 4) << 2);
#pragma unroll
  for (int i = 0; i < 4; i++) {
    int row = rowb + i * 16;
#pragma unroll
    for (int j = 0; j < 4; j++) {
      int cl = tN + wn * 64 + j * 16 + arow;
      if (cl >= N) continue;
      const OutDesc& d = (cl < Nsplit) ? o0 : o1;
      int c = (cl < Nsplit) ? cl : cl - Nsplit;
      long co = (long)z1 * d.s1 + (long)z2 * d.s2;
      float bv = d.bias ? d.bias[c] : 0.f;
      float x0 = acc[i][j][0] * alpha + bv;
      float x1 = acc[i][j][1] * alpha + bv;
      float x2 = acc[i][j][2] * alpha + bv;
      float x3 = acc[i][j][3] * alpha + bv;
      if (d.f) {
        d.f[co + (long)(row + 0) * d.ld + c] = x0;
        d.f[co + (long)(row + 1) * d.ld + c] = x1;
        d.f[co + (long)(row + 2) * d.ld + c] = x2;
        d.f[co + (long)(row + 3) * d.ld + c] = x3;
      }
      if (d.b) {
        d.b[co + (long)(row + 0) * d.ld + c] = f2b(x0);
        d.b[co + (long)(row + 1) * d.ld + c] = f2b(x1);
        d.b[co + (long)(row + 2) * d.ld + c] = f2b(x2);
        d.b[co + (long)(row + 3) * d.ld + c] = f2b(x3);
      }
      if (d.bt) {
        ushort4 v;
        v.x = f2b(x0); v.y = f2b(x1); v.z = f2b(x2); v.w = f2b(x3);
        *(ushort4*)(d.bt + co + (long)c * d.ldt + row) = v;
      }
    }
  }
}

// Split-K variant: blockIdx.z = z*SK + ks; each slice accumulates K range
// [ks*Kc, min(K,(ks+1)*Kc)) and atomicAdds fp32 partials into scratch C
// (layout [z][row][N] row-major, per-z stride cs). Scratch must be pre-zeroed.
// Rationale: the 256-row GEMMs launch only 40-80 blocks -> wall time is one
// block's serial K-latency chain (142us at 3% HBM). SK=8..16 multiplies grid
// occupancy and divides the chain length.
__global__ __launch_bounds__(256) void gemm_bt_sk(
    const u16* __restrict__ A, const u16* __restrict__ Bt,
    float* __restrict__ C, long cs,
    int N, int K, int Kc, int SK,
    long lda, long ldb, long sA1, long sA2, long sB1, long sB2,
    int Z1, float alpha)
{
  __shared__ __align__(16) u16 sm[8192];
  u16* As = sm;
  u16* Bs = sm + 4096;

  int zz = blockIdx.z;
  int ks = zz % SK;
  int z  = zz / SK;
  int z1 = z % Z1, z2 = z / Z1;
  const u16* Az = A + (long)z1 * sA1 + (long)z2 * sA2 + (long)blockIdx.x * 128 * lda;
  const u16* Bz = Bt + (long)z1 * sB1 + (long)z2 * sB2;

  int tN = blockIdx.y * 128;
  int t = threadIdx.x;
  int lane = t & 63, w = t >> 6;
  int wm = w & 1, wn = w >> 1;

  int rr = t >> 2;
  int c8 = (t & 3) << 3;
  int n0 = tN + rr;      if (n0 > N - 1) n0 = N - 1;
  int n1 = tN + 64 + rr; if (n1 > N - 1) n1 = N - 1;
  int kb = ks * Kc;
  int ke = kb + Kc; if (ke > K) ke = K;
  const u16* ga0 = Az + (long)rr * lda + kb + c8;
  const u16* ga1 = Az + (long)(rr + 64) * lda + kb + c8;
  const u16* gb0 = Bz + (long)n0 * ldb + kb + c8;
  const u16* gb1 = Bz + (long)n1 * ldb + kb + c8;
  u16* lA0 = As + t * 8;
  u16* lA1 = As + 2048 + t * 8;
  u16* lB0 = Bs + t * 8;
  u16* lB1 = Bs + 2048 + t * 8;

  f32x4 acc[4][4];
#pragma unroll
  for (int i = 0; i < 4; i++)
#pragma unroll
    for (int j = 0; j < 4; j++) acc[i][j] = (f32x4){0.f, 0.f, 0.f, 0.f};

  int arow = lane & 15;
  int kq = (lane >> 4) << 3;

  for (int k0 = kb; k0 < ke; k0 += 32) {
    gll16(ga0, lA0); gll16(ga1, lA1);
    gll16(gb0, lB0); gll16(gb1, lB1);
    ga0 += 32; ga1 += 32; gb0 += 32; gb1 += 32;
    __syncthreads();

    short8 af[4], bfr[4];
#pragma unroll
    for (int i = 0; i < 4; i++)
      af[i] = *(const short8*)(As + (wm * 64 + i * 16 + arow) * 32 + kq);
#pragma unroll
    for (int j = 0; j < 4; j++)
      bfr[j] = *(const short8*)(Bs + (wn * 64 + j * 16 + arow) * 32 + kq);
#pragma unroll
    for (int i = 0; i < 4; i++)
#pragma unroll
      for (int j = 0; j < 4; j++)
        acc[i][j] = __builtin_amdgcn_mfma_f32_16x16x32_bf16(af[i], bfr[j], acc[i][j], 0, 0, 0);
    __syncthreads();
  }

  int rowb = blockIdx.x * 128 + wm * 64 + ((lane >> 4) << 2);
  long zoff = (long)z * cs;
#pragma unroll
  for (int i = 0; i < 4; i++) {
    int row = rowb + i * 16;
#pragma unroll
    for (int j = 0; j < 4; j++) {
      int cl = tN + wn * 64 + j * 16 + arow;
      if (cl >= N) continue;
      float* cp = C + zoff + (long)row * N + cl;
      atomicAdd(cp,            acc[i][j][0] * alpha);
      atomicAdd(cp + N,        acc[i][j][1] * alpha);
      atomicAdd(cp + 2L * N,   acc[i][j][2] * alpha);
      atomicAdd(cp + 3L * N,   acc[i][j][3] * alpha);
    }
  }
}

// ---------------- helpers ----------------
__global__ void conv_bf16(const float* __restrict__ X, u16* __restrict__ Y, long n4) {
  long i = (long)blockIdx.x * 256 + threadIdx.x;
  if (i < n4) {
    float4 v = ((const float4*)X)[i];
    ushort4 o;
    o.x = f2b(v.x); o.y = f2b(v.y); o.z = f2b(v.z); o.w = f2b(v.w);
    ((ushort4*)Y)[i] = o;
  }
}

// W (K x N) fp32 -> Wt (N x K) bf16
__global__ __launch_bounds__(256) void transpose_conv(const float* __restrict__ W, u16* __restrict__ Wt, int K, int N) {
  __shared__ float tile[32][33];
  int nb = blockIdx.x * 32;
  int kb = blockIdx.y * 32;
  int tx = threadIdx.x & 31, ty = threadIdx.x >> 5;
  for (int r = ty; r < 32; r += 8) {
    int k = kb + r, n = nb + tx;
    tile[r][tx] = (k < K && n < N) ? W[(long)k * N + n] : 0.f;
  }
  __syncthreads();
  for (int r = ty; r < 32; r += 8) {
    int n = nb + r, k = kb + tx;
    if (n < N && k < K) Wt[(long)n * K + k] = f2b(tile[tx][r]);
  }
}

__global__ void init_mem(const float* __restrict__ im, float* __restrict__ mf, u16* __restrict__ mb,
                         long perB, long total) {
  long i = (long)blockIdx.x * 256 + threadIdx.x;
  if (i < total) { float v = im[i % perB]; mf[i] = v; mb[i] = f2b(v); }
}

__global__ __launch_bounds__(256) void softmax_rows(const float* __restrict__ S, u16* __restrict__ P, int len) {
  __shared__ float e[1024];
  __shared__ float red[4];
  long row = blockIdx.x;
  const float* x = S + row * (long)len;
  u16* pp = P + row * (long)len;
  int t = threadIdx.x;
  float mx = -3.4e38f;
  for (int i = t; i < len; i += 256) mx = fmaxf(mx, x[i]);
  for (int o = 32; o; o >>= 1) mx = fmaxf(mx, __shfl_xor(mx, o));
  if ((t & 63) == 0) red[t >> 6] = mx;
  __syncthreads();
  mx = fmaxf(fmaxf(red[0], red[1]), fmaxf(red[2], red[3]));
  __syncthreads();
  float sum = 0.f;
  for (int i = t; i < len; i += 256) { float v = __expf(x[i] - mx); e[i] = v; sum += v; }
  for (int o = 32; o; o >>= 1) sum += __shfl_xor(sum, o);
  if ((t & 63) == 0) red[t >> 6] = sum;
  __syncthreads();
  sum = red[0] + red[1] + red[2] + red[3];
  float inv = 1.f / sum;
  for (int i = t; i < len; i += 256) pp[i] = f2b(e[i] * inv);
}

__global__ void h_kernel(const float* __restrict__ hs, const float* __restrict__ gpre,
                         const float* __restrict__ o, float* __restrict__ out,
                         u16* __restrict__ hb, long segoff) {
  long idx = (long)blockIdx.x * 256 + threadIdx.x;
  const long per = (long)SEG * DDIM;
  long b = idx / per, r = idx - b * per;
  long io = b * (long)SS * DDIM + segoff + r;
  float g = 1.f / (1.f + __expf(-gpre[idx]));
  float h = hs[io] + g * o[idx];
  out[io] = h;
  hb[idx] = f2b(h);
}

__global__ void concat_mem(const u16* __restrict__ a, const u16* __restrict__ b, u16* __restrict__ c) {
  long idx = (long)blockIdx.x * 256 + threadIdx.x;
  long row = idx / (2 * DDIM);
  long col = idx - row * (2 * DDIM);
  c[idx] = (col < DDIM) ? a[row * DDIM + col] : b[row * DDIM + col - DDIM];
}

// g = sigmoid(scratch + bias[col]); mem = g*nm + (1-g)*mem   (bias fused here
// since the split-K gemm can no longer apply it in its epilogue)
__global__ void update_mem(const float* __restrict__ gp, const float* __restrict__ bias,
                           const float* __restrict__ nm,
                           float* __restrict__ mf, u16* __restrict__ mb) {
  long idx = (long)blockIdx.x * 256 + threadIdx.x;
  int col = (int)(idx % DDIM);
  float g = 1.f / (1.f + __expf(-(gp[idx] + bias[col])));
  float v = g * nm[idx] + (1.f - g) * mf[idx];
  mf[idx] = v;
  mb[idx] = f2b(v);
}

// ---- split-K finalize kernels ----

// scratch (B*M x 2D) fp32 -> k_r bf16 (B*M x D) for cols<D, v_rT bf16 (D x B*M) for cols>=D
__global__ __launch_bounds__(256) void fin_krv(const float* __restrict__ S,
                                               u16* __restrict__ kr, u16* __restrict__ vt) {
  __shared__ float tile[32][33];
  int cb = blockIdx.x * 32;   // col tile within 2D
  int rb = blockIdx.y * 32;   // row tile within B*M
  int tx = threadIdx.x & 31, ty = threadIdx.x >> 5;
  for (int r = ty; r < 32; r += 8) {
    float v = S[(long)(rb + r) * (2 * DDIM) + cb + tx];
    tile[r][tx] = v;
    if (cb + tx < DDIM) kr[(long)(rb + r) * DDIM + cb + tx] = f2b(v);
  }
  __syncthreads();
  if (cb >= DDIM) {
    for (int r = ty; r < 32; r += 8) {
      int col = cb + r - DDIM;
      vt[(long)col * (BB * MMEM) + rb + tx] = f2b(tile[tx][r]);
    }
  }
}

// scratch [z=16][M][HD] -> att bf16 at b*M*D + row*D + h*HD + col  (z1=h fast, z2=b)
__global__ void fin_attw(const float* __restrict__ S, u16* __restrict__ att) {
  long idx = (long)blockIdx.x * 256 + threadIdx.x;
  int col = (int)(idx % HDIM);
  long r = idx / HDIM;
  int row = (int)(r % MMEM);
  int z = (int)(r / MMEM);
  int h = z % NH, b = z / NH;
  att[(long)b * MMEM * DDIM + (long)row * DDIM + (long)h * HDIM + col] = f2b(S[idx]);
}

// scratch -> fp32 copy + bf16 copy (new_mem)
__global__ void fin_nm(const float* __restrict__ S, float* __restrict__ f, u16* __restrict__ b) {
  long idx = (long)blockIdx.x * 256 + threadIdx.x;
  float v = S[idx];
  f[idx] = v;
  b[idx] = f2b(v);
}

// scratch -> bf16 copy (q_w)
__global__ void fin_b16(const float* __restrict__ S, u16* __restrict__ b) {
  long idx = (long)blockIdx.x * 256 + threadIdx.x;
  b[idx] = f2b(S[idx]);
}

// ---------------- host ----------------
static inline OutDesc OD0() {
  OutDesc d; d.f = nullptr; d.b = nullptr; d.bt = nullptr; d.bias = nullptr;
  d.ld = 0; d.ldt = 0; d.s1 = 0; d.s2 = 0; return d;
}

static inline void launch_gemm(hipStream_t st, const void* A, const void* Bt,
    OutDesc o0, OutDesc o1, int Nsplit, int Mr, int N, int K,
    long lda, long ldb, long sA1, long sA2, long sB1, long sB2,
    int Z1, int Z2, float alpha)
{
  dim3 grid(Mr / 128, (N + 127) / 128, Z1 * Z2);
  gemm_bt<<<grid, dim3(256), 0, st>>>((const u16*)A, (const u16*)Bt, o0, o1,
      Nsplit, N, K, lda, ldb, sA1, sA2, sB1, sB2, Z1, alpha);
}

static inline void launch_gemm_sk(hipStream_t st, const void* A, const void* Bt,
    float* C, long cs, int Mr, int N, int K, int SK,
    long lda, long ldb, long sA1, long sA2, long sB1, long sB2,
    int Z1, int Z2, float alpha)
{
  dim3 grid(Mr / 128, (N + 127) / 128, Z1 * Z2 * SK);
  gemm_bt_sk<<<grid, dim3(256), 0, st>>>((const u16*)A, (const u16*)Bt, C, cs,
      N, K, K / SK, SK, lda, ldb, sA1, sA2, sB1, sB2, Z1, alpha);
}

extern "C" void kernel_launch(void* const* d_in, const int* in_sizes, int n_in,
                              void* d_out, int out_size, void* d_ws, size_t ws_size,
                              hipStream_t stream) {
  const float* hs   = (const float*)d_in[0];
  const float* imem = (const float*)d_in[1];
  const float* wq_r = (const float*)d_in[2];
  const float* wk_r = (const float*)d_in[3];
  const float* wv_r = (const float*)d_in[4];
  const float* wo_r = (const float*)d_in[5];
  const float* wg_r = (const float*)d_in[6];
  const float* bg_r = (const float*)d_in[7];
  const float* wqin = (const float*)d_in[8];
  const float* wq_w = (const float*)d_in[9];
  const float* wk_w = (const float*)d_in[10];
  const float* wv_w = (const float*)d_in[11];
  const float* wo_w = (const float*)d_in[12];
  const float* wg_w = (const float*)d_in[13];
  const float* bg_w = (const float*)d_in[14];
  float* out = (float*)d_out;

  const long D = DDIM, M = MMEM, S = SS, B = BB, H = NH, HD = HDIM, L = SEG;
  const float iscale = 1.f / sqrtf((float)HDIM);

  char* p = (char*)d_ws;
  auto alc = [&](size_t bytes) -> void* {
    void* r = (void*)p; p += (bytes + 255) & ~(size_t)255; return r;
  };

  u16* hs_b  = (u16*)alc(B * S * D * 2);
  u16* wqgT  = (u16*)alc(2 * D * D * 2);   // [wq_r^T ; wg_r^T]
  u16* wkvrT = (u16*)alc(2 * D * D * 2);   // [wk_r^T ; wv_r^T]
  u16* wkvwT = (u16*)alc(2 * D * D * 2);   // [wk_w^T ; wv_w^T]
  u16* worT  = (u16*)alc(D * D * 2);
  u16* wowT  = (u16*)alc(D * D * 2);
  u16* wqwT  = (u16*)alc(D * D * 2);
  u16* wgwT  = (u16*)alc(2 * D * D * 2);   // (D rows, 2D cols each row)
  u16* wq_b  = (u16*)alc(M * D * 2);
  u16* q_w   = (u16*)alc(M * D * 2);
  float* mem_f = (float*)alc(B * M * D * 4);
  u16*   mem_b = (u16*)alc(B * M * D * 2);
  float* nm_f  = (float*)alc(B * M * D * 4);
  u16*   nm_b  = (u16*)alc(B * M * D * 2);
  u16* q_r   = (u16*)alc(B * L * D * 2);
  u16* k_r   = (u16*)alc(B * M * D * 2);
  u16* v_rT  = (u16*)alc(D * B * M * 2);
  float* sc_r = (float*)alc(B * H * L * M * 4);
  u16*   pr_r = (u16*)alc(B * H * L * M * 2);
  u16* ctx   = (u16*)alc(B * L * D * 2);
  float* gpre = (float*)alc(B * L * D * 4);
  float* obuf = (float*)alc(B * L * D * 4);
  u16* h_b   = (u16*)alc(B * L * D * 2);
  u16* k_w   = (u16*)alc(B * L * D * 2);
  u16* v_wT  = (u16*)alc(D * B * L * 2);
  float* sc_w = (float*)alc(B * H * M * L * 4);
  u16*   pr_w = (u16*)alc(B * H * M * L * 2);
  u16* att_w = (u16*)alc(B * M * D * 2);
  u16* cat   = (u16*)alc(B * M * 2 * D * 2);
  float* skbuf = (float*)alc((size_t)(B * M) * 2 * D * 4);   // split-K scratch (5.25 MB)

  // ---- one-time preprocessing ----
  conv_bf16<<<(unsigned)((B * S * D / 4 + 255) / 256), 256, 0, stream>>>(hs, hs_b, B * S * D / 4);
  dim3 tg(D / 32, D / 32);
  transpose_conv<<<tg, 256, 0, stream>>>(wq_r, wqgT,          (int)D, (int)D);
  transpose_conv<<<tg, 256, 0, stream>>>(wg_r, wqgT + D * D,  (int)D, (int)D);
  transpose_conv<<<tg, 256, 0, stream>>>(wk_r, wkvrT,         (int)D, (int)D);
  transpose_conv<<<tg, 256, 0, stream>>>(wv_r, wkvrT + D * D, (int)D, (int)D);
  transpose_conv<<<tg, 256, 0, stream>>>(wk_w, wkvwT,         (int)D, (int)D);
  transpose_conv<<<tg, 256, 0, stream>>>(wv_w, wkvwT + D * D, (int)D, (int)D);
  transpose_conv<<<tg, 256, 0, stream>>>(wo_r, worT, (int)D, (int)D);
  transpose_conv<<<tg, 256, 0, stream>>>(wo_w, wowT, (int)D, (int)D);
  transpose_conv<<<tg, 256, 0, stream>>>(wq_w, wqwT, (int)D, (int)D);
  transpose_conv<<<dim3(D / 32, 2 * D / 32), 256, 0, stream>>>(wg_w, wgwT, (int)(2 * D), (int)D);
  conv_bf16<<<(unsigned)((M * D / 4 + 255) / 256), 256, 0, stream>>>(wqin, wq_b, M * D / 4);
  init_mem<<<(unsigned)((B * M * D + 255) / 256), 256, 0, stream>>>(imem, mem_f, mem_b, M * D, B * M * D);

  // q_w = write_queries @ wq_w  (batch/segment invariant) — split-K
  {
    hipMemsetAsync(skbuf, 0, (size_t)M * D * 4, stream);
    launch_gemm_sk(stream, wq_b, wqwT, skbuf, 0, (int)M, (int)D, (int)D, 8,
                   D, D, 0, 0, 0, 0, 1, 1, 1.f);
    fin_b16<<<(unsigned)(M * D / 256), 256, 0, stream>>>(skbuf, q_w);
  }

  for (int i = 0; i < NSEG; i++) {
    long so = (long)i * L * D;

    // [q_r | gpre] = seg @ [wq_r | wg_r]  (region0 bf16 q_r, region1 fp32+bias gpre)
    {
      OutDesc o0 = OD0(); o0.b = q_r;  o0.ld = D; o0.s2 = L * D;
      OutDesc o1 = OD0(); o1.f = gpre; o1.ld = D; o1.s2 = L * D; o1.bias = bg_r;
      launch_gemm(stream, hs_b + so, wqgT, o0, o1, (int)D, (int)L, (int)(2 * D), (int)D,
                  D, D, 0, S * D, 0, 0, 1, (int)B, 1.f);
    }
    // [k_r | v_rT] = mem @ [wk_r | wv_r] — split-K (grid was 80 blocks, 142us)
    {
      hipMemsetAsync(skbuf, 0, (size_t)(B * M) * 2 * D * 4, stream);
      launch_gemm_sk(stream, mem_b, wkvrT, skbuf, 0, (int)(B * M), (int)(2 * D), (int)D, 8,
                     D, D, 0, 0, 0, 0, 1, 1, 1.f);
      fin_krv<<<dim3((unsigned)(2 * D / 32), (unsigned)(B * M / 32)), 256, 0, stream>>>(skbuf, k_r, v_rT);
    }
    // scores_r = q_r . k_r^T / sqrt(hd) -> (B,H,L,M) fp32
    {
      OutDesc o0 = OD0(); o0.f = sc_r; o0.ld = M; o0.s1 = L * M; o0.s2 = H * L * M;
      launch_gemm(stream, q_r, k_r, o0, OD0(), (int)M, (int)L, (int)M, (int)HD,
                  D, D, HD, L * D, HD, M * D, (int)H, (int)B, iscale);
    }
    softmax_rows<<<(unsigned)(B * H * L), 256, 0, stream>>>(sc_r, pr_r, (int)M);
    // ctx = probs @ v -> (B,L,D) bf16
    {
      OutDesc o0 = OD0(); o0.b = ctx; o0.ld = D; o0.s1 = HD; o0.s2 = L * D;
      launch_gemm(stream, pr_r, v_rT, o0, OD0(), (int)HD, (int)L, (int)HD, (int)M,
                  M, B * M, L * M, H * L * M, HD * B * M, M, (int)H, (int)B, 1.f);
    }
    // obuf = ctx @ wo_r -> fp32
    {
      OutDesc o0 = OD0(); o0.f = obuf; o0.ld = D; o0.s2 = L * D;
      launch_gemm(stream, ctx, worT, o0, OD0(), (int)D, (int)L, (int)D, (int)D,
                  D, D, 0, L * D, 0, 0, 1, (int)B, 1.f);
    }
    h_kernel<<<(unsigned)(B * L * D / 256), 256, 0, stream>>>(hs, gpre, obuf, out, h_b, so);

    // [k_w | v_wT] = h @ [wk_w | wv_w]
    {
      OutDesc o0 = OD0(); o0.b = k_w;  o0.ld = D;
      OutDesc o1 = OD0(); o1.bt = v_wT; o1.ldt = B * L;
      launch_gemm(stream, h_b, wkvwT, o0, o1, (int)D, (int)(B * L), (int)(2 * D), (int)D,
                  D, D, 0, 0, 0, 0, 1, 1, 1.f);
    }
    // scores_w = q_w . k_w^T / sqrt(hd) -> (B,H,M,L) fp32
    {
      OutDesc o0 = OD0(); o0.f = sc_w; o0.ld = L; o0.s1 = M * L; o0.s2 = H * M * L;
      launch_gemm(stream, q_w, k_w, o0, OD0(), (int)L, (int)M, (int)L, (int)HD,
                  D, D, HD, 0, HD, L * D, (int)H, (int)B, iscale);
    }
    softmax_rows<<<(unsigned)(B * H * M), 256, 0, stream>>>(sc_w, pr_w, (int)L);
    // att_w = probs_w @ v_w -> (B,M,D) bf16 — split-K (grid was 48 blocks)
    {
      hipMemsetAsync(skbuf, 0, (size_t)B * H * M * HD * 4, stream);
      launch_gemm_sk(stream, pr_w, v_wT, skbuf, (long)M * HD, (int)M, (int)HD, (int)L, 4,
                     L, B * L, M * L, H * M * L, HD * B * L, L, (int)H, (int)B, 1.f);
      fin_attw<<<(unsigned)(B * H * M * HD / 256), 256, 0, stream>>>(skbuf, att_w);
    }
    // new_mem = att_w @ wo_w -> fp32 + bf16 — split-K (grid was 40 blocks)
    float* nmf = (i == 0) ? mem_f : nm_f;
    u16*   nmb = (i == 0) ? mem_b : nm_b;
    {
      hipMemsetAsync(skbuf, 0, (size_t)B * M * D * 4, stream);
      launch_gemm_sk(stream, att_w, wowT, skbuf, 0, (int)(B * M), (int)D, (int)D, 8,
                     D, D, 0, 0, 0, 0, 1, 1, 1.f);
      fin_nm<<<(unsigned)(B * M * D / 256), 256, 0, stream>>>(skbuf, nmf, nmb);
    }
    if (i > 0) {
      concat_mem<<<(unsigned)(B * M * 2 * D / 256), 256, 0, stream>>>(mem_b, nm_b, cat);
      // gpre_w = cat @ wgwT — split-K (grid was 40 blocks, 142us); bias fused in update_mem
      hipMemsetAsync(skbuf, 0, (size_t)B * M * D * 4, stream);
      launch_gemm_sk(stream, cat, wgwT, skbuf, 0, (int)(B * M), (int)D, (int)(2 * D), 16,
                     2 * D, 2 * D, 0, 0, 0, 0, 1, 1, 1.f);
      update_mem<<<(unsigned)(B * M * D / 256), 256, 0, stream>>>(skbuf, bg_w, nm_f, mem_f, mem_b);
    }
  }
}

// Round 3
// 2345.395 us; speedup vs baseline: 1.3658x; 1.0876x over previous
//
#include <hip/hip_runtime.h>
#include <hip/hip_bf16.h>
#include <math.h>

#define BB 2
#define SS 4096
#define DDIM 2560
#define MMEM 128
#define NH 8
#define HDIM 320
#define SEG 1024
#define NSEG 4

typedef unsigned short u16;
typedef __attribute__((ext_vector_type(8))) short short8;
typedef __attribute__((ext_vector_type(4))) float f32x4;

__device__ __forceinline__ u16 f2b(float x) {
  __hip_bfloat16 h = __float2bfloat16(x);
  return *reinterpret_cast<u16*>(&h);
}

__device__ __forceinline__ float b2f(u16 v) {
  unsigned int u = ((unsigned int)v) << 16;
  float f;
  __builtin_memcpy(&f, &u, 4);
  return f;
}

__device__ __forceinline__ void gll16(const u16* g, u16* l) {
  __builtin_amdgcn_global_load_lds(
      (__attribute__((address_space(1))) void*)g,
      (__attribute__((address_space(3))) void*)l, 16, 0, 0);
}

// Per-region output descriptor. Any non-null pointer gets written.
// f/b share geometry (ld, s1, s2); bt is bf16 transposed (ldt, s1, s2).
struct OutDesc {
  float* f; u16* b; u16* bt; const float* bias;
  long ld; long ldt; long s1; long s2;
};

// C = alpha * A @ Bt^T. A: (Mr x K) bf16 (Mr multiple of 128). Bt: (N x K) bf16.
// Region 0 covers cols [0,Nsplit), region 1 covers [Nsplit,N).
// 2-phase double-buffered K-loop: stage(next) || compute(cur), one barrier/step.
__global__ __launch_bounds__(256) void gemm_bt(
    const u16* __restrict__ A, const u16* __restrict__ Bt,
    OutDesc o0, OutDesc o1, int Nsplit,
    int N, int K, long lda, long ldb,
    long sA1, long sA2, long sB1, long sB2,
    int Z1, float alpha)
{
  __shared__ __align__(16) u16 sm[16384];  // 2 x (As[128][32] + Bs[128][32])

  int z = blockIdx.z;
  int z1 = z % Z1, z2 = z / Z1;
  const u16* Az = A + (long)z1 * sA1 + (long)z2 * sA2 + (long)blockIdx.x * 128 * lda;
  const u16* Bz = Bt + (long)z1 * sB1 + (long)z2 * sB2;

  int tN = blockIdx.y * 128;
  int t = threadIdx.x;
  int lane = t & 63, w = t >> 6;
  int wm = w & 1, wn = w >> 1;

  // ---- staging addresses (global_load_lds, 16B per lane) ----
  int rr = t >> 2;               // 0..63
  int c8 = (t & 3) << 3;         // 0,8,16,24
  int n0 = tN + rr;      if (n0 > N - 1) n0 = N - 1;   // clamp edge N tiles
  int n1 = tN + 64 + rr; if (n1 > N - 1) n1 = N - 1;
  const u16* ga0 = Az + (long)rr * lda + c8;
  const u16* ga1 = Az + (long)(rr + 64) * lda + c8;
  const u16* gb0 = Bz + (long)n0 * ldb + c8;
  const u16* gb1 = Bz + (long)n1 * ldb + c8;

  f32x4 acc[4][4];
#pragma unroll
  for (int i = 0; i < 4; i++)
#pragma unroll
    for (int j = 0; j < 4; j++) acc[i][j] = (f32x4){0.f, 0.f, 0.f, 0.f};

  int arow = lane & 15;
  int kq = (lane >> 4) << 3;

  auto stage = [&](u16* bb) {
    gll16(ga0, bb + t * 8);
    gll16(ga1, bb + 2048 + t * 8);
    gll16(gb0, bb + 4096 + t * 8);
    gll16(gb1, bb + 6144 + t * 8);
    ga0 += 32; ga1 += 32; gb0 += 32; gb1 += 32;
  };
  auto compute = [&](const u16* bb) {
    const u16* As = bb;
    const u16* Bs = bb + 4096;
    short8 af[4], bfr[4];
#pragma unroll
    for (int i = 0; i < 4; i++)
      af[i] = *(const short8*)(As + (wm * 64 + i * 16 + arow) * 32 + kq);
#pragma unroll
    for (int j = 0; j < 4; j++)
      bfr[j] = *(const short8*)(Bs + (wn * 64 + j * 16 + arow) * 32 + kq);
#pragma unroll
    for (int i = 0; i < 4; i++)
#pragma unroll
      for (int j = 0; j < 4; j++)
        acc[i][j] = __builtin_amdgcn_mfma_f32_16x16x32_bf16(af[i], bfr[j], acc[i][j], 0, 0, 0);
  };

  u16* b0 = sm;
  u16* b1 = sm + 8192;
  int nk = K / 32;
  stage(b0);
  __syncthreads();                       // loads for tile 0 landed
  for (int it = 1; it < nk; ++it) {
    u16* sb = (it & 1) ? b1 : b0;        // buffer staged this iter
    u16* cb = (it & 1) ? b0 : b1;        // buffer computed this iter (it-1's)
    stage(sb);                           // issue next-tile loads first
    compute(cb);                         // MFMA hides load flight time
    __syncthreads();                     // drains vmcnt + publishes sb; readers of cb done
  }
  compute(((nk - 1) & 1) ? b1 : b0);

  // ---- epilogue ----
  int rowb = blockIdx.x * 128 + wm * 64 + ((lane >> 4) << 2);
#pragma unroll
  for (int i = 0; i < 4; i++) {
    int row = rowb + i * 16;
#pragma unroll
    for (int j = 0; j < 4; j++) {
      int cl = tN + wn * 64 + j * 16 + arow;
      if (cl >= N) continue;
      const OutDesc& d = (cl < Nsplit) ? o0 : o1;
      int c = (cl < Nsplit) ? cl : cl - Nsplit;
      long co = (long)z1 * d.s1 + (long)z2 * d.s2;
      float bv = d.bias ? d.bias[c] : 0.f;
      float x0 = acc[i][j][0] * alpha + bv;
      float x1 = acc[i][j][1] * alpha + bv;
      float x2 = acc[i][j][2] * alpha + bv;
      float x3 = acc[i][j][3] * alpha + bv;
      if (d.f) {
        d.f[co + (long)(row + 0) * d.ld + c] = x0;
        d.f[co + (long)(row + 1) * d.ld + c] = x1;
        d.f[co + (long)(row + 2) * d.ld + c] = x2;
        d.f[co + (long)(row + 3) * d.ld + c] = x3;
      }
      if (d.b) {
        d.b[co + (long)(row + 0) * d.ld + c] = f2b(x0);
        d.b[co + (long)(row + 1) * d.ld + c] = f2b(x1);
        d.b[co + (long)(row + 2) * d.ld + c] = f2b(x2);
        d.b[co + (long)(row + 3) * d.ld + c] = f2b(x3);
      }
      if (d.bt) {
        ushort4 v;
        v.x = f2b(x0); v.y = f2b(x1); v.z = f2b(x2); v.w = f2b(x3);
        *(ushort4*)(d.bt + co + (long)c * d.ldt + row) = v;
      }
    }
  }
}

// Split-K variant: blockIdx.z = z*SK + ks; each slice accumulates K range
// [ks*Kc, min(K,(ks+1)*Kc)) and atomicAdds fp32 partials into scratch C
// (layout [z][row][N] row-major, per-z stride cs). Scratch must be pre-zeroed.
__global__ __launch_bounds__(256) void gemm_bt_sk(
    const u16* __restrict__ A, const u16* __restrict__ Bt,
    float* __restrict__ C, long cs,
    int N, int K, int Kc, int SK,
    long lda, long ldb, long sA1, long sA2, long sB1, long sB2,
    int Z1, float alpha)
{
  __shared__ __align__(16) u16 sm[16384];

  int zz = blockIdx.z;
  int ks = zz % SK;
  int z  = zz / SK;
  int z1 = z % Z1, z2 = z / Z1;
  const u16* Az = A + (long)z1 * sA1 + (long)z2 * sA2 + (long)blockIdx.x * 128 * lda;
  const u16* Bz = Bt + (long)z1 * sB1 + (long)z2 * sB2;

  int tN = blockIdx.y * 128;
  int t = threadIdx.x;
  int lane = t & 63, w = t >> 6;
  int wm = w & 1, wn = w >> 1;

  int rr = t >> 2;
  int c8 = (t & 3) << 3;
  int n0 = tN + rr;      if (n0 > N - 1) n0 = N - 1;
  int n1 = tN + 64 + rr; if (n1 > N - 1) n1 = N - 1;
  int kb = ks * Kc;
  int ke = kb + Kc; if (ke > K) ke = K;
  const u16* ga0 = Az + (long)rr * lda + kb + c8;
  const u16* ga1 = Az + (long)(rr + 64) * lda + kb + c8;
  const u16* gb0 = Bz + (long)n0 * ldb + kb + c8;
  const u16* gb1 = Bz + (long)n1 * ldb + kb + c8;

  f32x4 acc[4][4];
#pragma unroll
  for (int i = 0; i < 4; i++)
#pragma unroll
    for (int j = 0; j < 4; j++) acc[i][j] = (f32x4){0.f, 0.f, 0.f, 0.f};

  int arow = lane & 15;
  int kq = (lane >> 4) << 3;

  auto stage = [&](u16* bb) {
    gll16(ga0, bb + t * 8);
    gll16(ga1, bb + 2048 + t * 8);
    gll16(gb0, bb + 4096 + t * 8);
    gll16(gb1, bb + 6144 + t * 8);
    ga0 += 32; ga1 += 32; gb0 += 32; gb1 += 32;
  };
  auto compute = [&](const u16* bb) {
    const u16* As = bb;
    const u16* Bs = bb + 4096;
    short8 af[4], bfr[4];
#pragma unroll
    for (int i = 0; i < 4; i++)
      af[i] = *(const short8*)(As + (wm * 64 + i * 16 + arow) * 32 + kq);
#pragma unroll
    for (int j = 0; j < 4; j++)
      bfr[j] = *(const short8*)(Bs + (wn * 64 + j * 16 + arow) * 32 + kq);
#pragma unroll
    for (int i = 0; i < 4; i++)
#pragma unroll
      for (int j = 0; j < 4; j++)
        acc[i][j] = __builtin_amdgcn_mfma_f32_16x16x32_bf16(af[i], bfr[j], acc[i][j], 0, 0, 0);
  };

  u16* b0 = sm;
  u16* b1 = sm + 8192;
  int nk = (ke - kb) / 32;
  stage(b0);
  __syncthreads();
  for (int it = 1; it < nk; ++it) {
    u16* sb = (it & 1) ? b1 : b0;
    u16* cb = (it & 1) ? b0 : b1;
    stage(sb);
    compute(cb);
    __syncthreads();
  }
  compute(((nk - 1) & 1) ? b1 : b0);

  int rowb = blockIdx.x * 128 + wm * 64 + ((lane >> 4) << 2);
  long zoff = (long)z * cs;
#pragma unroll
  for (int i = 0; i < 4; i++) {
    int row = rowb + i * 16;
#pragma unroll
    for (int j = 0; j < 4; j++) {
      int cl = tN + wn * 64 + j * 16 + arow;
      if (cl >= N) continue;
      float* cp = C + zoff + (long)row * N + cl;
      atomicAdd(cp,            acc[i][j][0] * alpha);
      atomicAdd(cp + N,        acc[i][j][1] * alpha);
      atomicAdd(cp + 2L * N,   acc[i][j][2] * alpha);
      atomicAdd(cp + 3L * N,   acc[i][j][3] * alpha);
    }
  }
}

// ---------------- helpers ----------------
__global__ void conv_bf16(const float* __restrict__ X, u16* __restrict__ Y, long n4) {
  long i = (long)blockIdx.x * 256 + threadIdx.x;
  if (i < n4) {
    float4 v = ((const float4*)X)[i];
    ushort4 o;
    o.x = f2b(v.x); o.y = f2b(v.y); o.z = f2b(v.z); o.w = f2b(v.w);
    ((ushort4*)Y)[i] = o;
  }
}

// W (K x N) fp32 -> Wt (N x K) bf16
__global__ __launch_bounds__(256) void transpose_conv(const float* __restrict__ W, u16* __restrict__ Wt, int K, int N) {
  __shared__ float tile[32][33];
  int nb = blockIdx.x * 32;
  int kb = blockIdx.y * 32;
  int tx = threadIdx.x & 31, ty = threadIdx.x >> 5;
  for (int r = ty; r < 32; r += 8) {
    int k = kb + r, n = nb + tx;
    tile[r][tx] = (k < K && n < N) ? W[(long)k * N + n] : 0.f;
  }
  __syncthreads();
  for (int r = ty; r < 32; r += 8) {
    int n = nb + r, k = kb + tx;
    if (n < N && k < K) Wt[(long)n * K + k] = f2b(tile[tx][r]);
  }
}

__global__ void init_mem(const float* __restrict__ im, float* __restrict__ mf, u16* __restrict__ mb,
                         long perB, long total) {
  long i = (long)blockIdx.x * 256 + threadIdx.x;
  if (i < total) { float v = im[i % perB]; mf[i] = v; mb[i] = f2b(v); }
}

__global__ __launch_bounds__(256) void softmax_rows(const float* __restrict__ S, u16* __restrict__ P, int len) {
  __shared__ float e[1024];
  __shared__ float red[4];
  long row = blockIdx.x;
  const float* x = S + row * (long)len;
  u16* pp = P + row * (long)len;
  int t = threadIdx.x;
  float mx = -3.4e38f;
  for (int i = t; i < len; i += 256) mx = fmaxf(mx, x[i]);
  for (int o = 32; o; o >>= 1) mx = fmaxf(mx, __shfl_xor(mx, o));
  if ((t & 63) == 0) red[t >> 6] = mx;
  __syncthreads();
  mx = fmaxf(fmaxf(red[0], red[1]), fmaxf(red[2], red[3]));
  __syncthreads();
  float sum = 0.f;
  for (int i = t; i < len; i += 256) { float v = __expf(x[i] - mx); e[i] = v; sum += v; }
  for (int o = 32; o; o >>= 1) sum += __shfl_xor(sum, o);
  if ((t & 63) == 0) red[t >> 6] = sum;
  __syncthreads();
  sum = red[0] + red[1] + red[2] + red[3];
  float inv = 1.f / sum;
  for (int i = t; i < len; i += 256) pp[i] = f2b(e[i] * inv);
}

// gpre is bf16, indexed like hs/out (full B,S,D layout, hoisted)
__global__ void h_kernel(const float* __restrict__ hs, const u16* __restrict__ gpre_b,
                         const float* __restrict__ o, float* __restrict__ out,
                         u16* __restrict__ hb, long segoff) {
  long idx = (long)blockIdx.x * 256 + threadIdx.x;
  const long per = (long)SEG * DDIM;
  long b = idx / per, r = idx - b * per;
  long io = b * (long)SS * DDIM + segoff + r;
  float g = 1.f / (1.f + __expf(-b2f(gpre_b[io])));
  float h = hs[io] + g * o[idx];
  out[io] = h;
  hb[idx] = f2b(h);
}

__global__ void concat_mem(const u16* __restrict__ a, const u16* __restrict__ b, u16* __restrict__ c) {
  long idx = (long)blockIdx.x * 256 + threadIdx.x;
  long row = idx / (2 * DDIM);
  long col = idx - row * (2 * DDIM);
  c[idx] = (col < DDIM) ? a[row * DDIM + col] : b[row * DDIM + col - DDIM];
}

// g = sigmoid(scratch + bias[col]); mem = g*nm + (1-g)*mem
__global__ void update_mem(const float* __restrict__ gp, const float* __restrict__ bias,
                           const float* __restrict__ nm,
                           float* __restrict__ mf, u16* __restrict__ mb) {
  long idx = (long)blockIdx.x * 256 + threadIdx.x;
  int col = (int)(idx % DDIM);
  float g = 1.f / (1.f + __expf(-(gp[idx] + bias[col])));
  float v = g * nm[idx] + (1.f - g) * mf[idx];
  mf[idx] = v;
  mb[idx] = f2b(v);
}

// ---- split-K finalize kernels ----

// scratch (B*M x 2D) fp32 -> k_r bf16 (B*M x D) for cols<D, v_rT bf16 (D x B*M) for cols>=D
__global__ __launch_bounds__(256) void fin_krv(const float* __restrict__ S,
                                               u16* __restrict__ kr, u16* __restrict__ vt) {
  __shared__ float tile[32][33];
  int cb = blockIdx.x * 32;   // col tile within 2D
  int rb = blockIdx.y * 32;   // row tile within B*M
  int tx = threadIdx.x & 31, ty = threadIdx.x >> 5;
  for (int r = ty; r < 32; r += 8) {
    float v = S[(long)(rb + r) * (2 * DDIM) + cb + tx];
    tile[r][tx] = v;
    if (cb + tx < DDIM) kr[(long)(rb + r) * DDIM + cb + tx] = f2b(v);
  }
  __syncthreads();
  if (cb >= DDIM) {
    for (int r = ty; r < 32; r += 8) {
      int col = cb + r - DDIM;
      vt[(long)col * (BB * MMEM) + rb + tx] = f2b(tile[tx][r]);
    }
  }
}

// scratch [z=16][M][HD] -> att bf16 at b*M*D + row*D + h*HD + col  (z1=h fast, z2=b)
__global__ void fin_attw(const float* __restrict__ S, u16* __restrict__ att) {
  long idx = (long)blockIdx.x * 256 + threadIdx.x;
  int col = (int)(idx % HDIM);
  long r = idx / HDIM;
  int row = (int)(r % MMEM);
  int z = (int)(r / MMEM);
  int h = z % NH, b = z / NH;
  att[(long)b * MMEM * DDIM + (long)row * DDIM + (long)h * HDIM + col] = f2b(S[idx]);
}

// scratch -> fp32 copy + bf16 copy (new_mem)
__global__ void fin_nm(const float* __restrict__ S, float* __restrict__ f, u16* __restrict__ b) {
  long idx = (long)blockIdx.x * 256 + threadIdx.x;
  float v = S[idx];
  f[idx] = v;
  b[idx] = f2b(v);
}

// scratch -> bf16 copy (q_w)
__global__ void fin_b16(const float* __restrict__ S, u16* __restrict__ b) {
  long idx = (long)blockIdx.x * 256 + threadIdx.x;
  b[idx] = f2b(S[idx]);
}

// ---------------- host ----------------
static inline OutDesc OD0() {
  OutDesc d; d.f = nullptr; d.b = nullptr; d.bt = nullptr; d.bias = nullptr;
  d.ld = 0; d.ldt = 0; d.s1 = 0; d.s2 = 0; return d;
}

static inline void launch_gemm(hipStream_t st, const void* A, const void* Bt,
    OutDesc o0, OutDesc o1, int Nsplit, int Mr, int N, int K,
    long lda, long ldb, long sA1, long sA2, long sB1, long sB2,
    int Z1, int Z2, float alpha)
{
  dim3 grid(Mr / 128, (N + 127) / 128, Z1 * Z2);
  gemm_bt<<<grid, dim3(256), 0, st>>>((const u16*)A, (const u16*)Bt, o0, o1,
      Nsplit, N, K, lda, ldb, sA1, sA2, sB1, sB2, Z1, alpha);
}

static inline void launch_gemm_sk(hipStream_t st, const void* A, const void* Bt,
    float* C, long cs, int Mr, int N, int K, int SK,
    long lda, long ldb, long sA1, long sA2, long sB1, long sB2,
    int Z1, int Z2, float alpha)
{
  dim3 grid(Mr / 128, (N + 127) / 128, Z1 * Z2 * SK);
  gemm_bt_sk<<<grid, dim3(256), 0, st>>>((const u16*)A, (const u16*)Bt, C, cs,
      N, K, K / SK, SK, lda, ldb, sA1, sA2, sB1, sB2, Z1, alpha);
}

extern "C" void kernel_launch(void* const* d_in, const int* in_sizes, int n_in,
                              void* d_out, int out_size, void* d_ws, size_t ws_size,
                              hipStream_t stream) {
  const float* hs   = (const float*)d_in[0];
  const float* imem = (const float*)d_in[1];
  const float* wq_r = (const float*)d_in[2];
  const float* wk_r = (const float*)d_in[3];
  const float* wv_r = (const float*)d_in[4];
  const float* wo_r = (const float*)d_in[5];
  const float* wg_r = (const float*)d_in[6];
  const float* bg_r = (const float*)d_in[7];
  const float* wqin = (const float*)d_in[8];
  const float* wq_w = (const float*)d_in[9];
  const float* wk_w = (const float*)d_in[10];
  const float* wv_w = (const float*)d_in[11];
  const float* wo_w = (const float*)d_in[12];
  const float* wg_w = (const float*)d_in[13];
  const float* bg_w = (const float*)d_in[14];
  float* out = (float*)d_out;

  const long D = DDIM, M = MMEM, S = SS, B = BB, H = NH, HD = HDIM, L = SEG;
  const float iscale = 1.f / sqrtf((float)HDIM);

  char* p = (char*)d_ws;
  auto alc = [&](size_t bytes) -> void* {
    void* r = (void*)p; p += (bytes + 255) & ~(size_t)255; return r;
  };

  // ---- workspace budget: round-1 layout (326.6 MB) was proven; round-2's
  // +52 MB overflowed -> crash. This layout overlays per-segment transients
  // into hs_b (dead after the hoisted gemm) and unions h_b/pr_w. Total ~301 MB.
  u16* hs_b  = (u16*)alc(B * S * D * 2);   // 41,943,040 B; dead after hoisted gemm
  // overlays inside hs_b (live ranges strictly sequential, audited):
  //   [0,20.97M):        sc_r -> obuf -> sc_w   (fp32)
  //   [20.97M,31.46M):   ctx  -> k_w            (bf16)
  //   [31.46M,41.94M):   pr_r -> v_wT           (bf16)
  float* scr  = (float*)hs_b;
  u16*  ctxkw = (u16*)((char*)hs_b + 20971520);
  u16*  prvw  = (u16*)((char*)hs_b + 31457280);

  u16* wqgT  = (u16*)alc(2 * D * D * 2);   // [wq_r^T ; wg_r^T]
  u16* wkvrT = (u16*)alc(2 * D * D * 2);   // [wk_r^T ; wv_r^T]
  u16* wkvwT = (u16*)alc(2 * D * D * 2);   // [wk_w^T ; wv_w^T]
  u16* worT  = (u16*)alc(D * D * 2);
  u16* wowT  = (u16*)alc(D * D * 2);
  u16* wqwT  = (u16*)alc(D * D * 2);
  u16* wgwT  = (u16*)alc(2 * D * D * 2);   // (D rows, 2D cols each row)
  u16* wq_b  = (u16*)alc(M * D * 2);
  u16* q_w   = (u16*)alc(M * D * 2);
  float* mem_f = (float*)alc(B * M * D * 4);
  u16*   mem_b = (u16*)alc(B * M * D * 2);
  float* nm_f  = (float*)alc(B * M * D * 4);
  u16*   nm_b  = (u16*)alc(B * M * D * 2);
  u16* q_r    = (u16*)alc(B * S * D * 2);  // ALL segments (hoisted)
  u16* gpre_b = (u16*)alc(B * S * D * 2);  // ALL segments, bf16 (hoisted)
  u16* k_r   = (u16*)alc(B * M * D * 2);
  u16* v_rT  = (u16*)alc(D * B * M * 2);
  u16* hbpw  = (u16*)alc(B * L * D * 2);   // union: h_b -> pr_w
  u16* att_w = (u16*)alc(B * M * D * 2);
  u16* cat   = (u16*)alc(B * M * 2 * D * 2);
  float* skbuf = (float*)alc((size_t)(B * M) * 2 * D * 4);   // split-K scratch (5.25 MB)

  // ---- one-time preprocessing ----
  conv_bf16<<<(unsigned)((B * S * D / 4 + 255) / 256), 256, 0, stream>>>(hs, hs_b, B * S * D / 4);
  dim3 tg(D / 32, D / 32);
  transpose_conv<<<tg, 256, 0, stream>>>(wq_r, wqgT,          (int)D, (int)D);
  transpose_conv<<<tg, 256, 0, stream>>>(wg_r, wqgT + D * D,  (int)D, (int)D);
  transpose_conv<<<tg, 256, 0, stream>>>(wk_r, wkvrT,         (int)D, (int)D);
  transpose_conv<<<tg, 256, 0, stream>>>(wv_r, wkvrT + D * D, (int)D, (int)D);
  transpose_conv<<<tg, 256, 0, stream>>>(wk_w, wkvwT,         (int)D, (int)D);
  transpose_conv<<<tg, 256, 0, stream>>>(wv_w, wkvwT + D * D, (int)D, (int)D);
  transpose_conv<<<tg, 256, 0, stream>>>(wo_r, worT, (int)D, (int)D);
  transpose_conv<<<tg, 256, 0, stream>>>(wo_w, wowT, (int)D, (int)D);
  transpose_conv<<<tg, 256, 0, stream>>>(wq_w, wqwT, (int)D, (int)D);
  transpose_conv<<<dim3(D / 32, 2 * D / 32), 256, 0, stream>>>(wg_w, wgwT, (int)(2 * D), (int)D);
  conv_bf16<<<(unsigned)((M * D / 4 + 255) / 256), 256, 0, stream>>>(wqin, wq_b, M * D / 4);
  init_mem<<<(unsigned)((B * M * D + 255) / 256), 256, 0, stream>>>(imem, mem_f, mem_b, M * D, B * M * D);

  // q_w = write_queries @ wq_w  (batch/segment invariant) — split-K
  {
    hipMemsetAsync(skbuf, 0, (size_t)M * D * 4, stream);
    launch_gemm_sk(stream, wq_b, wqwT, skbuf, 0, (int)M, (int)D, (int)D, 8,
                   D, D, 0, 0, 0, 0, 1, 1, 1.f);
    fin_b16<<<(unsigned)(M * D / 256), 256, 0, stream>>>(skbuf, q_w);
  }

  // HOISTED: [q_r | gpre] = hs @ [wq_r | wg_r] for ALL segments at once.
  // A = (B*S, D) contiguous rows -> grid 64x40 = 2560 blocks (10/CU) vs 4x640.
  // hs_b is dead after this dispatch; its bytes are reused by the overlays.
  {
    OutDesc o0 = OD0(); o0.b = q_r;    o0.ld = D;
    OutDesc o1 = OD0(); o1.b = gpre_b; o1.ld = D; o1.bias = bg_r;
    launch_gemm(stream, hs_b, wqgT, o0, o1, (int)D, (int)(B * S), (int)(2 * D), (int)D,
                D, D, 0, 0, 0, 0, 1, 1, 1.f);
  }

  for (int i = 0; i < NSEG; i++) {
    long so = (long)i * L * D;

    // [k_r | v_rT] = mem @ [wk_r | wv_r] — split-K
    {
      hipMemsetAsync(skbuf, 0, (size_t)(B * M) * 2 * D * 4, stream);
      launch_gemm_sk(stream, mem_b, wkvrT, skbuf, 0, (int)(B * M), (int)(2 * D), (int)D, 8,
                     D, D, 0, 0, 0, 0, 1, 1, 1.f);
      fin_krv<<<dim3((unsigned)(2 * D / 32), (unsigned)(B * M / 32)), 256, 0, stream>>>(skbuf, k_r, v_rT);
    }
    // scores_r = q_r . k_r^T / sqrt(hd) -> (B,H,L,M) fp32 in scr
    {
      OutDesc o0 = OD0(); o0.f = scr; o0.ld = M; o0.s1 = L * M; o0.s2 = H * L * M;
      launch_gemm(stream, q_r + so, k_r, o0, OD0(), (int)M, (int)L, (int)M, (int)HD,
                  D, D, HD, S * D, HD, M * D, (int)H, (int)B, iscale);
    }
    softmax_rows<<<(unsigned)(B * H * L), 256, 0, stream>>>(scr, prvw, (int)M);   // pr_r
    // ctx = probs @ v -> (B,L,D) bf16 in ctxkw
    {
      OutDesc o0 = OD0(); o0.b = ctxkw; o0.ld = D; o0.s1 = HD; o0.s2 = L * D;
      launch_gemm(stream, prvw, v_rT, o0, OD0(), (int)HD, (int)L, (int)HD, (int)M,
                  M, B * M, L * M, H * L * M, HD * B * M, M, (int)H, (int)B, 1.f);
    }
    // obuf = ctx @ wo_r -> fp32 in scr (sc_r dead)
    {
      OutDesc o0 = OD0(); o0.f = scr; o0.ld = D; o0.s2 = L * D;
      launch_gemm(stream, ctxkw, worT, o0, OD0(), (int)D, (int)L, (int)D, (int)D,
                  D, D, 0, L * D, 0, 0, 1, (int)B, 1.f);
    }
    h_kernel<<<(unsigned)(B * L * D / 256), 256, 0, stream>>>(hs, gpre_b, scr, out, hbpw, so);

    // [k_w | v_wT] = h @ [wk_w | wv_w]  (k_w -> ctxkw, v_wT -> prvw; ctx/pr_r dead)
    {
      OutDesc o0 = OD0(); o0.b = ctxkw;  o0.ld = D;
      OutDesc o1 = OD0(); o1.bt = prvw; o1.ldt = B * L;
      launch_gemm(stream, hbpw, wkvwT, o0, o1, (int)D, (int)(B * L), (int)(2 * D), (int)D,
                  D, D, 0, 0, 0, 0, 1, 1, 1.f);
    }
    // scores_w = q_w . k_w^T / sqrt(hd) -> (B,H,M,L) fp32 in scr (obuf dead)
    {
      OutDesc o0 = OD0(); o0.f = scr; o0.ld = L; o0.s1 = M * L; o0.s2 = H * M * L;
      launch_gemm(stream, q_w, ctxkw, o0, OD0(), (int)L, (int)M, (int)L, (int)HD,
                  D, D, HD, 0, HD, L * D, (int)H, (int)B, iscale);
    }
    softmax_rows<<<(unsigned)(B * H * M), 256, 0, stream>>>(scr, hbpw, (int)L);   // pr_w (h_b dead)
    // att_w = probs_w @ v_w -> (B,M,D) bf16 — split-K
    {
      hipMemsetAsync(skbuf, 0, (size_t)B * H * M * HD * 4, stream);
      launch_gemm_sk(stream, hbpw, prvw, skbuf, (long)M * HD, (int)M, (int)HD, (int)L, 4,
                     L, B * L, M * L, H * M * L, HD * B * L, L, (int)H, (int)B, 1.f);
      fin_attw<<<(unsigned)(B * H * M * HD / 256), 256, 0, stream>>>(skbuf, att_w);
    }
    // new_mem = att_w @ wo_w -> fp32 + bf16 — split-K
    float* nmf = (i == 0) ? mem_f : nm_f;
    u16*   nmb = (i == 0) ? mem_b : nm_b;
    {
      hipMemsetAsync(skbuf, 0, (size_t)B * M * D * 4, stream);
      launch_gemm_sk(stream, att_w, wowT, skbuf, 0, (int)(B * M), (int)D, (int)D, 8,
                     D, D, 0, 0, 0, 0, 1, 1, 1.f);
      fin_nm<<<(unsigned)(B * M * D / 256), 256, 0, stream>>>(skbuf, nmf, nmb);
    }
    if (i > 0) {
      concat_mem<<<(unsigned)(B * M * 2 * D / 256), 256, 0, stream>>>(mem_b, nm_b, cat);
      // gpre_w = cat @ wgwT — split-K; bias fused in update_mem
      hipMemsetAsync(skbuf, 0, (size_t)B * M * D * 4, stream);
      launch_gemm_sk(stream, cat, wgwT, skbuf, 0, (int)(B * M), (int)D, (int)(2 * D), 16,
                     2 * D, 2 * D, 0, 0, 0, 0, 1, 1, 1.f);
      update_mem<<<(unsigned)(B * M * D / 256), 256, 0, stream>>>(skbuf, bg_w, nm_f, mem_f, mem_b);
    }
  }
}